// Round 1
// baseline (203.228 us; speedup 1.0000x reference)
//
#include <hip/hip_runtime.h>
#include <cstdint>

// ECT loss, exact elementwise formulation (R1 math preserved bit-for-bit).
// A[bc][r][d] = sum_p dw[b,p,c] * sigmoid(8*(lin_r - <x_p, v_d>)), c in {0,1};
// c2 = -(c0+c1); loss = mean over 12288.
//
// This round (occupancy + fusion):
//  * 512 blocks x 512 threads. Two 256-thread subgroups each process 108 of
//    the block's 216 voxels -> 16 waves/CU (4/SIMD, 50% occ) vs 8 before,
//    while per-block atomic count stays 8192 (cross-subgroup LDS reduce).
//  * Etab precompute: E = exp(8*<x,v>) computed once per (voxel, dir) into
//    LDS instead of once per (voxel, dir, rg-group): -3 fma -1 mul -1 exp
//    -1 ds_read_b128 per voxel-thread in the hot loop.
//  * ect_fin fused via last-block-done counter (threadfence + atomicAdd
//    ticket; last block reads gacc with agent-scope atomic loads). Graph is
//    now memset + 1 kernel.
//
// ws: gacc[4][8192] floats + counter = 128 KB + 64 B.

#define P_TOT 110592
#define VOXB 216   // voxels per block
#define VOXS 108   // voxels per 256-thread subgroup
#define NREP 4
#define GRID 512

__device__ __forceinline__ uint32_t rotl32(uint32_t x, int d) {
  return (x << d) | (x >> (32 - d));
}

// threefry2x32, key = (0,17) — bit-exact vs jax (verified R1-R3)
__device__ __forceinline__ void threefry_0_17(uint32_t x0, uint32_t x1,
                                              uint32_t& o0, uint32_t& o1) {
  const uint32_t ks0 = 0u, ks1 = 17u, ks2 = 0x1BD11BDAu ^ 0u ^ 17u;
  x0 += ks0; x1 += ks1;
#define R4(a,b,c,dd) \
  x0 += x1; x1 = rotl32(x1,(a)); x1 ^= x0; \
  x0 += x1; x1 = rotl32(x1,(b)); x1 ^= x0; \
  x0 += x1; x1 = rotl32(x1,(c)); x1 ^= x0; \
  x0 += x1; x1 = rotl32(x1,(dd)); x1 ^= x0;
  R4(13,15,26,6)   x0 += ks1; x1 += ks2 + 1u;
  R4(17,29,16,24)  x0 += ks2; x1 += ks0 + 2u;
  R4(13,15,26,6)   x0 += ks0; x1 += ks1 + 3u;
  R4(17,29,16,24)  x0 += ks1; x1 += ks2 + 4u;
  R4(13,15,26,6)   x0 += ks2; x1 += ks0 + 5u;
#undef R4
  o0 = x0; o1 = x1;
}

// XLA ErfInv32 — bit-exact vs jax (verified R1-R3)
__device__ __forceinline__ float erfinv_f32(float x) {
  float w = -log1pf(-x * x);
  float p;
  if (w < 5.0f) {
    w = w - 2.5f;
    p = 2.81022636e-08f;
    p = fmaf(p, w, 3.43273939e-07f);
    p = fmaf(p, w, -3.5233877e-06f);
    p = fmaf(p, w, -4.39150654e-06f);
    p = fmaf(p, w, 0.00021858087f);
    p = fmaf(p, w, -0.00125372503f);
    p = fmaf(p, w, -0.00417768164f);
    p = fmaf(p, w, 0.246640727f);
    p = fmaf(p, w, 1.50140941f);
  } else {
    w = sqrtf(w) - 3.0f;
    p = -0.000200214257f;
    p = fmaf(p, w, 0.000100950558f);
    p = fmaf(p, w, 0.00134934322f);
    p = fmaf(p, w, 0.000337081863f);
    p = fmaf(p, w, 0.00573950773f);
    p = fmaf(p, w, -0.0076224613f);
    p = fmaf(p, w, 0.00943887047f);
    p = fmaf(p, w, 1.00167406f);
    p = fmaf(p, w, 2.83297682f);
  }
  return p * x;
}

__global__ __launch_bounds__(512, 4) void ect_main(
    const float* __restrict__ pred, const int* __restrict__ tgt,
    float* __restrict__ gacc, float* __restrict__ out) {
  __shared__ float dirs[96];          // [3][32] unit directions
  __shared__ float4 voxdw[VOXB];      // (b0c0,b0c1,b1c0,b1c1)
  __shared__ float Etab[VOXB * 32];   // exp(8*<x_v, dir_d>) per (v,d) — 27.6 KB
  __shared__ float red[32 * 256];     // cross-subgroup reduce — 32 KB
  __shared__ float redf[8];
  __shared__ int islast;

  const int t = threadIdx.x;
  const int bx = blockIdx.x;
  const int sub = t >> 8;             // subgroup 0/1
  const int tl = t & 255;             // lane within subgroup
  const int d = tl & 31;
  const int rg = tl >> 5;
  const int cbase = bx * VOXB;

  // ---- init: directions (raw normals) ----
  if (t < 96) {
    uint32_t o0, o1;
    threefry_0_17(0u, (uint32_t)t, o0, o1);
    uint32_t bits = o0 ^ o1;
    float u = __uint_as_float((bits >> 9) | 0x3F800000u) - 1.0f;
    const float lo = -0.99999994f;
    float v = fmaf(u, 2.0f, lo);
    v = fmaxf(v, lo);
    dirs[t] = 1.41421356237f * erfinv_f32(v);
  }
  __syncthreads();
  if (t < 32) {
    float a = dirs[t], b = dirs[32 + t], c = dirs[64 + t];
    float n = fmaxf(sqrtf(a * a + b * b + c * c), 1e-12f);
    dirs[t] = a / n; dirs[32 + t] = b / n; dirs[64 + t] = c / n;
  }
  // ---- init: per-voxel dw (softmax - onehot) ----
  if (t < VOXB) {
    int p = cbase + t;
    float w[4];
#pragma unroll
    for (int b = 0; b < 2; b++) {
      const float* pb = pred + b * (3 * P_TOT) + p;
      float x0 = pb[0], x1 = pb[P_TOT], x2 = pb[2 * P_TOT];
      float m = fmaxf(x0, fmaxf(x1, x2));
      float e0 = __expf(x0 - m), e1 = __expf(x1 - m), e2 = __expf(x2 - m);
      float inv = 1.0f / (e0 + e1 + e2);
      int tg = tgt[b * P_TOT + p];
      w[b * 2 + 0] = e0 * inv - ((tg == 0) ? 1.0f : 0.0f);
      w[b * 2 + 1] = e1 * inv - ((tg == 1) ? 1.0f : 0.0f);
    }
    voxdw[t] = float4{w[0], w[1], w[2], w[3]};
  }
  __syncthreads();

  // ---- init: Etab[v][d] = exp(8 * <x_v, dir_d>) — hoists the per-rg
  //      duplicated nh+exp out of the hot loop ----
  for (int i = t; i < VOXB * 32; i += 512) {
    int v = i >> 5, dd = i & 31;
    int p = cbase + v;
    int ix = p / 2304; int rem = p - ix * 2304;
    int iy = rem / 48; int iz = rem - iy * 48;
    const float delta = 2.0f / 47.0f;
    float cx = (float)ix * delta - 1.0f;
    float cy = (float)iy * delta - 1.0f;
    float cz = (float)iz * delta - 1.0f;
    float nh = fmaf(cz, dirs[64 + dd], fmaf(cy, dirs[32 + dd], cx * dirs[dd]));
    Etab[i] = __expf(8.0f * nh);       // <= e^13.9, no overflow
  }
  __syncthreads();

  // per-thread constants
  const float radius = 1.1f * 1.7320508075688772f;
  const float step = (2.0f * radius) / 63.0f;
  float K[8];
#pragma unroll
  for (int j = 0; j < 8; j++) {
    float lin = fmaf((float)(rg * 8 + j), step, -radius);
    K[j] = __expf(-8.0f * lin);
  }

  float acc[8][4];
#pragma unroll
  for (int j = 0; j < 8; j++)
#pragma unroll
    for (int bc = 0; bc < 4; bc++) acc[j][bc] = 0.0f;

  // ---- main loop: barrier-free, VALU-bound; each subgroup owns 108 voxels ----
  const int vbeg = sub * VOXS;
#pragma unroll 4
  for (int v = vbeg; v < vbeg + VOXS; v++) {
    float4 w = voxdw[v];
    float E = Etab[(v << 5) + d];             // conflict-free broadcast read
    float z[8];
#pragma unroll
    for (int j = 0; j < 8; j++) z[j] = fmaf(E, K[j], 1.0f);  // 1..4.4e12
#pragma unroll
    for (int h = 0; h < 4; h++) {
      // paired reciprocal: product <= 2e25, no overflow
      float pz = z[2 * h] * z[2 * h + 1];
      float rr = __builtin_amdgcn_rcpf(pz);
      float s0 = z[2 * h + 1] * rr;           // sigmoid for r = rg*8+2h
      float s1 = z[2 * h] * rr;               // sigmoid for r = rg*8+2h+1
      acc[2 * h][0] = fmaf(w.x, s0, acc[2 * h][0]);
      acc[2 * h][1] = fmaf(w.y, s0, acc[2 * h][1]);
      acc[2 * h][2] = fmaf(w.z, s0, acc[2 * h][2]);
      acc[2 * h][3] = fmaf(w.w, s0, acc[2 * h][3]);
      acc[2 * h + 1][0] = fmaf(w.x, s1, acc[2 * h + 1][0]);
      acc[2 * h + 1][1] = fmaf(w.y, s1, acc[2 * h + 1][1]);
      acc[2 * h + 1][2] = fmaf(w.z, s1, acc[2 * h + 1][2]);
      acc[2 * h + 1][3] = fmaf(w.w, s1, acc[2 * h + 1][3]);
    }
  }

  // ---- cross-subgroup reduce: sub1 -> LDS, sub0 accumulates ----
  if (sub == 1) {
#pragma unroll
    for (int j = 0; j < 8; j++)
#pragma unroll
      for (int bc = 0; bc < 4; bc++)
        red[(j * 4 + bc) * 256 + tl] = acc[j][bc];  // lane-consecutive: no conflicts
  }
  __syncthreads();

  // ---- epilogue: scatter-atomic into replica (8192 atomics/block, as before) ----
  if (sub == 0) {
    float* grep = gacc + (size_t)(bx & (NREP - 1)) * 8192;
#pragma unroll
    for (int j = 0; j < 8; j++) {
#pragma unroll
      for (int bc = 0; bc < 4; bc++)
        acc[j][bc] += red[(j * 4 + bc) * 256 + tl];
      int base = ((rg * 8 + j) * 32 + d) * 4;
      atomicAdd(&grep[base + 0], acc[j][0]);
      atomicAdd(&grep[base + 1], acc[j][1]);
      atomicAdd(&grep[base + 2], acc[j][2]);
      atomicAdd(&grep[base + 3], acc[j][3]);
    }
  }

  // ---- fused finalizer: last block to arrive reduces gacc -> out ----
  __threadfence();                    // release this block's atomics
  __syncthreads();
  unsigned int* cnt = (unsigned int*)(gacc + (size_t)NREP * 8192);
  if (t == 0) {
    unsigned int old = atomicAdd(cnt, 1u);
    islast = (old == (unsigned int)(GRID - 1)) ? 1 : 0;
  }
  __syncthreads();
  if (islast) {
    __threadfence();                  // acquire side
    float s = 0.0f;
    for (int i = t; i < 2048; i += 512) {   // i = r*32 + d
      float a0 = 0.f, a1 = 0.f, a2 = 0.f, a3 = 0.f;
#pragma unroll
      for (int rep = 0; rep < NREP; rep++) {
        const unsigned long long* p64 =
            (const unsigned long long*)(gacc + (size_t)rep * 8192 + i * 4);
        unsigned long long q0 = __hip_atomic_load(p64, __ATOMIC_RELAXED,
                                                  __HIP_MEMORY_SCOPE_AGENT);
        unsigned long long q1 = __hip_atomic_load(p64 + 1, __ATOMIC_RELAXED,
                                                  __HIP_MEMORY_SCOPE_AGENT);
        a0 += __uint_as_float((unsigned int)q0);
        a1 += __uint_as_float((unsigned int)(q0 >> 32));
        a2 += __uint_as_float((unsigned int)q1);
        a3 += __uint_as_float((unsigned int)(q1 >> 32));
      }
      s += a0 * a0 + a1 * a1 + (a0 + a1) * (a0 + a1)
         + a2 * a2 + a3 * a3 + (a2 + a3) * (a2 + a3);
    }
#pragma unroll
    for (int off = 32; off > 0; off >>= 1) s += __shfl_down(s, off, 64);
    if ((t & 63) == 0) redf[t >> 6] = s;
    __syncthreads();
    if (t == 0) {
      float r2 = redf[0] + redf[1] + redf[2] + redf[3]
               + redf[4] + redf[5] + redf[6] + redf[7];
      out[0] = r2 * (1.0f / 12288.0f);
    }
  }
}

extern "C" void kernel_launch(void* const* d_in, const int* in_sizes, int n_in,
                              void* d_out, int out_size, void* d_ws, size_t ws_size,
                              hipStream_t stream) {
  const float* pred = (const float*)d_in[0];
  const int* tgt = (const int*)d_in[1];
  float* gacc = (float*)d_ws;                  // 4*8192 floats + counter
  float* out = (float*)d_out;

  hipMemsetAsync(gacc, 0, (size_t)NREP * 8192 * sizeof(float) + 64, stream);
  hipLaunchKernelGGL(ect_main, dim3(GRID), dim3(512), 0, stream,
                     pred, tgt, gacc, out);
}

// Round 2
// 151.495 us; speedup vs baseline: 1.3415x; 1.3415x over previous
//
#include <hip/hip_runtime.h>
#include <cstdint>

// ECT loss, exact elementwise formulation (R1 math, absmax 0.0).
// A[bc][r][d] = sum_p dw[b,p,c] * sigmoid(8*(lin_r - <x_p, v_d>)), c in {0,1};
// c2 = -(c0+c1); loss = mean over 12288.
//
// R2: revert to the proven 93-us R0 main structure (256 thr, 216 vox/block,
// E recomputed in-register, barrier-free loop, 32 VGPR). Two separable deltas:
//  * fused finalizer via last-block ticket. NO __threadfence: __syncthreads()
//    already drains vmcnt(0) per wave (completing this block's device-scope
//    atomics at the coherent point) before the ticket atomic. Last block reads
//    gacc with agent-scope atomic loads (empirically exact in R1).
//  * NREP 4 -> 8: halves same-address atomic contention (64 blocks/replica).
//
// ws: gacc[8][8192] floats + counter = 256 KB + 64 B.

#define P_TOT 110592
#define VOX 216
#define NREP 8
#define GRID 512

__device__ __forceinline__ uint32_t rotl32(uint32_t x, int d) {
  return (x << d) | (x >> (32 - d));
}

// threefry2x32, key = (0,17) — bit-exact vs jax (verified R1-R3)
__device__ __forceinline__ void threefry_0_17(uint32_t x0, uint32_t x1,
                                              uint32_t& o0, uint32_t& o1) {
  const uint32_t ks0 = 0u, ks1 = 17u, ks2 = 0x1BD11BDAu ^ 0u ^ 17u;
  x0 += ks0; x1 += ks1;
#define R4(a,b,c,dd) \
  x0 += x1; x1 = rotl32(x1,(a)); x1 ^= x0; \
  x0 += x1; x1 = rotl32(x1,(b)); x1 ^= x0; \
  x0 += x1; x1 = rotl32(x1,(c)); x1 ^= x0; \
  x0 += x1; x1 = rotl32(x1,(dd)); x1 ^= x0;
  R4(13,15,26,6)   x0 += ks1; x1 += ks2 + 1u;
  R4(17,29,16,24)  x0 += ks2; x1 += ks0 + 2u;
  R4(13,15,26,6)   x0 += ks0; x1 += ks1 + 3u;
  R4(17,29,16,24)  x0 += ks1; x1 += ks2 + 4u;
  R4(13,15,26,6)   x0 += ks2; x1 += ks0 + 5u;
#undef R4
  o0 = x0; o1 = x1;
}

// XLA ErfInv32 — bit-exact vs jax (verified R1-R3)
__device__ __forceinline__ float erfinv_f32(float x) {
  float w = -log1pf(-x * x);
  float p;
  if (w < 5.0f) {
    w = w - 2.5f;
    p = 2.81022636e-08f;
    p = fmaf(p, w, 3.43273939e-07f);
    p = fmaf(p, w, -3.5233877e-06f);
    p = fmaf(p, w, -4.39150654e-06f);
    p = fmaf(p, w, 0.00021858087f);
    p = fmaf(p, w, -0.00125372503f);
    p = fmaf(p, w, -0.00417768164f);
    p = fmaf(p, w, 0.246640727f);
    p = fmaf(p, w, 1.50140941f);
  } else {
    w = sqrtf(w) - 3.0f;
    p = -0.000200214257f;
    p = fmaf(p, w, 0.000100950558f);
    p = fmaf(p, w, 0.00134934322f);
    p = fmaf(p, w, 0.000337081863f);
    p = fmaf(p, w, 0.00573950773f);
    p = fmaf(p, w, -0.0076224613f);
    p = fmaf(p, w, 0.00943887047f);
    p = fmaf(p, w, 1.00167406f);
    p = fmaf(p, w, 2.83297682f);
  }
  return p * x;
}

__global__ __launch_bounds__(256, 2) void ect_main(
    const float* __restrict__ pred, const int* __restrict__ tgt,
    float* __restrict__ gacc, float* __restrict__ out) {
  __shared__ float dirs[96];        // [3][32] unit directions
  __shared__ float4 voxdw[VOX];     // (b0c0,b0c1,b1c0,b1c1)
  __shared__ float4 voxc[VOX];      // (cx,cy,cz,-)
  __shared__ float redf[4];
  __shared__ int islast;

  const int t = threadIdx.x;
  const int bx = blockIdx.x;
  const int d = t & 31;
  const int rg = t >> 5;
  const int cbase = bx * VOX;

  // ---- init: directions (raw normals) ----
  if (t < 96) {
    uint32_t o0, o1;
    threefry_0_17(0u, (uint32_t)t, o0, o1);
    uint32_t bits = o0 ^ o1;
    float u = __uint_as_float((bits >> 9) | 0x3F800000u) - 1.0f;
    const float lo = -0.99999994f;
    float v = fmaf(u, 2.0f, lo);
    v = fmaxf(v, lo);
    dirs[t] = 1.41421356237f * erfinv_f32(v);
  }
  __syncthreads();
  if (t < 32) {
    float a = dirs[t], b = dirs[32 + t], c = dirs[64 + t];
    float n = fmaxf(sqrtf(a * a + b * b + c * c), 1e-12f);
    dirs[t] = a / n; dirs[32 + t] = b / n; dirs[64 + t] = c / n;
  }
  // ---- init: per-voxel dw (softmax - onehot) and coords ----
  if (t < VOX) {
    int p = cbase + t;
    int ix = p / 2304; int rem = p - ix * 2304;
    int iy = rem / 48; int iz = rem - iy * 48;
    const float delta = 2.0f / 47.0f;
    voxc[t] = float4{(float)ix * delta - 1.0f, (float)iy * delta - 1.0f,
                     (float)iz * delta - 1.0f, 0.0f};
    float w[4];
#pragma unroll
    for (int b = 0; b < 2; b++) {
      const float* pb = pred + b * (3 * P_TOT) + p;
      float x0 = pb[0], x1 = pb[P_TOT], x2 = pb[2 * P_TOT];
      float m = fmaxf(x0, fmaxf(x1, x2));
      float e0 = __expf(x0 - m), e1 = __expf(x1 - m), e2 = __expf(x2 - m);
      float inv = 1.0f / (e0 + e1 + e2);
      int tg = tgt[b * P_TOT + p];
      w[b * 2 + 0] = e0 * inv - ((tg == 0) ? 1.0f : 0.0f);
      w[b * 2 + 1] = e1 * inv - ((tg == 1) ? 1.0f : 0.0f);
    }
    voxdw[t] = float4{w[0], w[1], w[2], w[3]};
  }
  __syncthreads();

  // per-thread constants
  const float dir0 = dirs[d], dir1 = dirs[32 + d], dir2 = dirs[64 + d];
  const float radius = 1.1f * 1.7320508075688772f;
  const float step = (2.0f * radius) / 63.0f;
  float K[8];
#pragma unroll
  for (int j = 0; j < 8; j++) {
    float lin = fmaf((float)(rg * 8 + j), step, -radius);
    K[j] = __expf(-8.0f * lin);
  }

  float acc[8][4];
#pragma unroll
  for (int j = 0; j < 8; j++)
#pragma unroll
    for (int bc = 0; bc < 4; bc++) acc[j][bc] = 0.0f;

  // ---- main loop: barrier-free, VALU-bound ----
#pragma unroll 4
  for (int v = 0; v < VOX; v++) {
    float4 c = voxc[v];
    float4 w = voxdw[v];
    float nh = fmaf(c.z, dir2, fmaf(c.y, dir1, c.x * dir0));
    float E = __expf(8.0f * nh);              // <= e^13.9, no overflow
    float z[8];
#pragma unroll
    for (int j = 0; j < 8; j++) z[j] = fmaf(E, K[j], 1.0f);  // 1..4.4e12
#pragma unroll
    for (int h = 0; h < 4; h++) {
      // paired reciprocal: product <= 2e25, no overflow
      float pz = z[2 * h] * z[2 * h + 1];
      float rr = __builtin_amdgcn_rcpf(pz);
      float s0 = z[2 * h + 1] * rr;           // sigmoid for r = rg*8+2h
      float s1 = z[2 * h] * rr;               // sigmoid for r = rg*8+2h+1
      acc[2 * h][0] = fmaf(w.x, s0, acc[2 * h][0]);
      acc[2 * h][1] = fmaf(w.y, s0, acc[2 * h][1]);
      acc[2 * h][2] = fmaf(w.z, s0, acc[2 * h][2]);
      acc[2 * h][3] = fmaf(w.w, s0, acc[2 * h][3]);
      acc[2 * h + 1][0] = fmaf(w.x, s1, acc[2 * h + 1][0]);
      acc[2 * h + 1][1] = fmaf(w.y, s1, acc[2 * h + 1][1]);
      acc[2 * h + 1][2] = fmaf(w.z, s1, acc[2 * h + 1][2]);
      acc[2 * h + 1][3] = fmaf(w.w, s1, acc[2 * h + 1][3]);
    }
  }

  // ---- epilogue: scatter-atomic into replica ----
  float* grep = gacc + (size_t)(bx & (NREP - 1)) * 8192;
#pragma unroll
  for (int j = 0; j < 8; j++) {
    int base = ((rg * 8 + j) * 32 + d) * 4;
    atomicAdd(&grep[base + 0], acc[j][0]);
    atomicAdd(&grep[base + 1], acc[j][1]);
    atomicAdd(&grep[base + 2], acc[j][2]);
    atomicAdd(&grep[base + 3], acc[j][3]);
  }

  // ---- fused finalizer: last block to arrive reduces gacc -> out ----
  // __syncthreads() emits s_waitcnt vmcnt(0) per wave before s_barrier, which
  // completes this block's device-scope atomics at the coherent point. No
  // __threadfence (R1's per-wave device fence was a prime regression suspect).
  __syncthreads();
  unsigned int* cnt = (unsigned int*)(gacc + (size_t)NREP * 8192);
  if (t == 0) {
    unsigned int old = __hip_atomic_fetch_add(cnt, 1u, __ATOMIC_RELAXED,
                                              __HIP_MEMORY_SCOPE_AGENT);
    islast = (old == (unsigned int)(GRID - 1)) ? 1 : 0;
  }
  __syncthreads();
  if (islast) {
    float s = 0.0f;
    for (int i = t; i < 2048; i += 256) {   // i = r*32 + d
      float a0 = 0.f, a1 = 0.f, a2 = 0.f, a3 = 0.f;
#pragma unroll
      for (int rep = 0; rep < NREP; rep++) {
        const unsigned long long* p64 =
            (const unsigned long long*)(gacc + (size_t)rep * 8192 + i * 4);
        unsigned long long q0 = __hip_atomic_load(p64, __ATOMIC_RELAXED,
                                                  __HIP_MEMORY_SCOPE_AGENT);
        unsigned long long q1 = __hip_atomic_load(p64 + 1, __ATOMIC_RELAXED,
                                                  __HIP_MEMORY_SCOPE_AGENT);
        a0 += __uint_as_float((unsigned int)q0);
        a1 += __uint_as_float((unsigned int)(q0 >> 32));
        a2 += __uint_as_float((unsigned int)q1);
        a3 += __uint_as_float((unsigned int)(q1 >> 32));
      }
      s += a0 * a0 + a1 * a1 + (a0 + a1) * (a0 + a1)
         + a2 * a2 + a3 * a3 + (a2 + a3) * (a2 + a3);
    }
#pragma unroll
    for (int off = 32; off > 0; off >>= 1) s += __shfl_down(s, off, 64);
    if ((t & 63) == 0) redf[t >> 6] = s;
    __syncthreads();
    if (t == 0) {
      out[0] = (redf[0] + redf[1] + redf[2] + redf[3]) * (1.0f / 12288.0f);
    }
  }
}

extern "C" void kernel_launch(void* const* d_in, const int* in_sizes, int n_in,
                              void* d_out, int out_size, void* d_ws, size_t ws_size,
                              hipStream_t stream) {
  const float* pred = (const float*)d_in[0];
  const int* tgt = (const int*)d_in[1];
  float* gacc = (float*)d_ws;                  // 8*8192 floats + counter
  float* out = (float*)d_out;

  hipMemsetAsync(gacc, 0, (size_t)NREP * 8192 * sizeof(float) + 64, stream);
  hipLaunchKernelGGL(ect_main, dim3(GRID), dim3(256), 0, stream,
                     pred, tgt, gacc, out);
}

// Round 3
// 114.527 us; speedup vs baseline: 1.7745x; 1.3228x over previous
//
#include <hip/hip_runtime.h>
#include <cstdint>

// ECT loss, exact elementwise formulation (R1 math, absmax 0.0).
// A[bc][r][d] = sum_p dw[b,p,c] * sigmoid(8*(lin_r - <x_p, v_d>)), c in {0,1};
// c2 = -(c0+c1); loss = mean over 12288.
//
// R3: eliminate the device-scope atomic drain from ect_main.
// Theory: 4.19M fp32 atomics (all issued in one burst when the single
// co-resident round of 512 blocks finishes) serialize at the memory-side
// atomic units (~55 us tail; WRITE_SIZE showed 16 B/atomic write-through).
// ect_main now writes per-block partials with plain coalesced float4 stores
// (part[512][8192] = 16 MB, fire-and-forget); ect_red (128 blocks) reduces
// slices with coalesced reads + only 131K atomics (16/address) and computes
// the final MSE via last-block ticket.
//
// ws (store path): part 16 MB + gacc2 32 KB + ticket. Host falls back to the
// proven R0 atomic path if ws_size is too small.

#define P_TOT 110592
#define VOX 216
#define GRID 512
#define NREP 4  // fallback path only

__device__ __forceinline__ uint32_t rotl32(uint32_t x, int d) {
  return (x << d) | (x >> (32 - d));
}

// threefry2x32, key = (0,17) — bit-exact vs jax (verified R1-R3)
__device__ __forceinline__ void threefry_0_17(uint32_t x0, uint32_t x1,
                                              uint32_t& o0, uint32_t& o1) {
  const uint32_t ks0 = 0u, ks1 = 17u, ks2 = 0x1BD11BDAu ^ 0u ^ 17u;
  x0 += ks0; x1 += ks1;
#define R4(a,b,c,dd) \
  x0 += x1; x1 = rotl32(x1,(a)); x1 ^= x0; \
  x0 += x1; x1 = rotl32(x1,(b)); x1 ^= x0; \
  x0 += x1; x1 = rotl32(x1,(c)); x1 ^= x0; \
  x0 += x1; x1 = rotl32(x1,(dd)); x1 ^= x0;
  R4(13,15,26,6)   x0 += ks1; x1 += ks2 + 1u;
  R4(17,29,16,24)  x0 += ks2; x1 += ks0 + 2u;
  R4(13,15,26,6)   x0 += ks0; x1 += ks1 + 3u;
  R4(17,29,16,24)  x0 += ks1; x1 += ks2 + 4u;
  R4(13,15,26,6)   x0 += ks2; x1 += ks0 + 5u;
#undef R4
  o0 = x0; o1 = x1;
}

// XLA ErfInv32 — bit-exact vs jax (verified R1-R3)
__device__ __forceinline__ float erfinv_f32(float x) {
  float w = -log1pf(-x * x);
  float p;
  if (w < 5.0f) {
    w = w - 2.5f;
    p = 2.81022636e-08f;
    p = fmaf(p, w, 3.43273939e-07f);
    p = fmaf(p, w, -3.5233877e-06f);
    p = fmaf(p, w, -4.39150654e-06f);
    p = fmaf(p, w, 0.00021858087f);
    p = fmaf(p, w, -0.00125372503f);
    p = fmaf(p, w, -0.00417768164f);
    p = fmaf(p, w, 0.246640727f);
    p = fmaf(p, w, 1.50140941f);
  } else {
    w = sqrtf(w) - 3.0f;
    p = -0.000200214257f;
    p = fmaf(p, w, 0.000100950558f);
    p = fmaf(p, w, 0.00134934322f);
    p = fmaf(p, w, 0.000337081863f);
    p = fmaf(p, w, 0.00573950773f);
    p = fmaf(p, w, -0.0076224613f);
    p = fmaf(p, w, 0.00943887047f);
    p = fmaf(p, w, 1.00167406f);
    p = fmaf(p, w, 2.83297682f);
  }
  return p * x;
}

// ---------- shared device helpers for the main compute ----------
__device__ __forceinline__ void ect_block_compute(
    const float* __restrict__ pred, const int* __restrict__ tgt,
    float* dirs, float4* voxdw, float4* voxc,
    int t, int bx, float acc[8][4]) {
  const int d = t & 31;
  const int rg = t >> 5;
  const int cbase = bx * VOX;

  if (t < 96) {
    uint32_t o0, o1;
    threefry_0_17(0u, (uint32_t)t, o0, o1);
    uint32_t bits = o0 ^ o1;
    float u = __uint_as_float((bits >> 9) | 0x3F800000u) - 1.0f;
    const float lo = -0.99999994f;
    float v = fmaf(u, 2.0f, lo);
    v = fmaxf(v, lo);
    dirs[t] = 1.41421356237f * erfinv_f32(v);
  }
  __syncthreads();
  if (t < 32) {
    float a = dirs[t], b = dirs[32 + t], c = dirs[64 + t];
    float n = fmaxf(sqrtf(a * a + b * b + c * c), 1e-12f);
    dirs[t] = a / n; dirs[32 + t] = b / n; dirs[64 + t] = c / n;
  }
  if (t < VOX) {
    int p = cbase + t;
    int ix = p / 2304; int rem = p - ix * 2304;
    int iy = rem / 48; int iz = rem - iy * 48;
    const float delta = 2.0f / 47.0f;
    voxc[t] = float4{(float)ix * delta - 1.0f, (float)iy * delta - 1.0f,
                     (float)iz * delta - 1.0f, 0.0f};
    float w[4];
#pragma unroll
    for (int b = 0; b < 2; b++) {
      const float* pb = pred + b * (3 * P_TOT) + p;
      float x0 = pb[0], x1 = pb[P_TOT], x2 = pb[2 * P_TOT];
      float m = fmaxf(x0, fmaxf(x1, x2));
      float e0 = __expf(x0 - m), e1 = __expf(x1 - m), e2 = __expf(x2 - m);
      float inv = 1.0f / (e0 + e1 + e2);
      int tg = tgt[b * P_TOT + p];
      w[b * 2 + 0] = e0 * inv - ((tg == 0) ? 1.0f : 0.0f);
      w[b * 2 + 1] = e1 * inv - ((tg == 1) ? 1.0f : 0.0f);
    }
    voxdw[t] = float4{w[0], w[1], w[2], w[3]};
  }
  __syncthreads();

  const float dir0 = dirs[d], dir1 = dirs[32 + d], dir2 = dirs[64 + d];
  const float radius = 1.1f * 1.7320508075688772f;
  const float step = (2.0f * radius) / 63.0f;
  float K[8];
#pragma unroll
  for (int j = 0; j < 8; j++) {
    float lin = fmaf((float)(rg * 8 + j), step, -radius);
    K[j] = __expf(-8.0f * lin);
  }
#pragma unroll
  for (int j = 0; j < 8; j++)
#pragma unroll
    for (int bc = 0; bc < 4; bc++) acc[j][bc] = 0.0f;

#pragma unroll 4
  for (int v = 0; v < VOX; v++) {
    float4 c = voxc[v];
    float4 w = voxdw[v];
    float nh = fmaf(c.z, dir2, fmaf(c.y, dir1, c.x * dir0));
    float E = __expf(8.0f * nh);              // <= e^13.9, no overflow
    float z[8];
#pragma unroll
    for (int j = 0; j < 8; j++) z[j] = fmaf(E, K[j], 1.0f);  // 1..4.4e12
#pragma unroll
    for (int h = 0; h < 4; h++) {
      // paired reciprocal: product <= 2e25, no overflow
      float pz = z[2 * h] * z[2 * h + 1];
      float rr = __builtin_amdgcn_rcpf(pz);
      float s0 = z[2 * h + 1] * rr;
      float s1 = z[2 * h] * rr;
      acc[2 * h][0] = fmaf(w.x, s0, acc[2 * h][0]);
      acc[2 * h][1] = fmaf(w.y, s0, acc[2 * h][1]);
      acc[2 * h][2] = fmaf(w.z, s0, acc[2 * h][2]);
      acc[2 * h][3] = fmaf(w.w, s0, acc[2 * h][3]);
      acc[2 * h + 1][0] = fmaf(w.x, s1, acc[2 * h + 1][0]);
      acc[2 * h + 1][1] = fmaf(w.y, s1, acc[2 * h + 1][1]);
      acc[2 * h + 1][2] = fmaf(w.z, s1, acc[2 * h + 1][2]);
      acc[2 * h + 1][3] = fmaf(w.w, s1, acc[2 * h + 1][3]);
    }
  }
}

// ---------- store path: ect_main_st + ect_red ----------
__global__ __launch_bounds__(256, 2) void ect_main_st(
    const float* __restrict__ pred, const int* __restrict__ tgt,
    float* __restrict__ part) {
  __shared__ float dirs[96];
  __shared__ float4 voxdw[VOX];
  __shared__ float4 voxc[VOX];
  const int t = threadIdx.x;
  const int bx = blockIdx.x;
  const int d = t & 31;
  const int rg = t >> 5;
  float acc[8][4];
  ect_block_compute(pred, tgt, dirs, voxdw, voxc, t, bx, acc);

  // pure coalesced stores: part[bx][(r*32+d)*4 + bc]
  float4* prt = (float4*)part + (size_t)bx * 2048;
#pragma unroll
  for (int j = 0; j < 8; j++) {
    prt[(rg * 8 + j) * 32 + d] =
        float4{acc[j][0], acc[j][1], acc[j][2], acc[j][3]};
  }
}

__global__ __launch_bounds__(256) void ect_red(
    const float* __restrict__ part, float* __restrict__ gacc2,
    float* __restrict__ out) {
  __shared__ float redf[4];
  __shared__ int islast;
  const int t = threadIdx.x;
  const int rc = blockIdx.x >> 3;       // 0..15 slice chunk (32 slices)
  const int cc = blockIdx.x & 7;        // 0..7 column chunk (256 float4)
  const int c4 = cc * 256 + t;          // float4 column in [0, 2048)
  const float4* p4 = (const float4*)part;

  float a0 = 0.f, a1 = 0.f, a2 = 0.f, a3 = 0.f;
#pragma unroll 8
  for (int r = rc * 32; r < rc * 32 + 32; ++r) {
    float4 v = p4[(size_t)r * 2048 + c4];   // 1KB-coalesced per wave per r
    a0 += v.x; a1 += v.y; a2 += v.z; a3 += v.w;
  }
  // 16 contenders per address — cheap
  atomicAdd(&gacc2[c4 * 4 + 0], a0);
  atomicAdd(&gacc2[c4 * 4 + 1], a1);
  atomicAdd(&gacc2[c4 * 4 + 2], a2);
  atomicAdd(&gacc2[c4 * 4 + 3], a3);

  // last-block ticket -> final MSE
  __syncthreads();                       // drains vmcnt(0) per wave
  unsigned int* cnt = (unsigned int*)(gacc2 + 8192);
  if (t == 0) {
    unsigned int old = __hip_atomic_fetch_add(cnt, 1u, __ATOMIC_RELAXED,
                                              __HIP_MEMORY_SCOPE_AGENT);
    islast = (old == 127u) ? 1 : 0;
  }
  __syncthreads();
  if (islast) {
    float s = 0.0f;
    for (int i = t; i < 2048; i += 256) {  // i = r*32 + d
      const unsigned long long* p64 =
          (const unsigned long long*)(gacc2 + i * 4);
      unsigned long long q0 = __hip_atomic_load(p64, __ATOMIC_RELAXED,
                                                __HIP_MEMORY_SCOPE_AGENT);
      unsigned long long q1 = __hip_atomic_load(p64 + 1, __ATOMIC_RELAXED,
                                                __HIP_MEMORY_SCOPE_AGENT);
      float b0 = __uint_as_float((unsigned int)q0);
      float b1 = __uint_as_float((unsigned int)(q0 >> 32));
      float b2 = __uint_as_float((unsigned int)q1);
      float b3 = __uint_as_float((unsigned int)(q1 >> 32));
      s += b0 * b0 + b1 * b1 + (b0 + b1) * (b0 + b1)
         + b2 * b2 + b3 * b3 + (b2 + b3) * (b2 + b3);
    }
#pragma unroll
    for (int off = 32; off > 0; off >>= 1) s += __shfl_down(s, off, 64);
    if ((t & 63) == 0) redf[t >> 6] = s;
    __syncthreads();
    if (t == 0)
      out[0] = (redf[0] + redf[1] + redf[2] + redf[3]) * (1.0f / 12288.0f);
  }
}

// ---------- fallback path (proven R0 structure): atomic main + fin ----------
__global__ __launch_bounds__(256, 2) void ect_main_at(
    const float* __restrict__ pred, const int* __restrict__ tgt,
    float* __restrict__ gacc) {
  __shared__ float dirs[96];
  __shared__ float4 voxdw[VOX];
  __shared__ float4 voxc[VOX];
  const int t = threadIdx.x;
  const int bx = blockIdx.x;
  const int d = t & 31;
  const int rg = t >> 5;
  float acc[8][4];
  ect_block_compute(pred, tgt, dirs, voxdw, voxc, t, bx, acc);

  float* grep = gacc + (size_t)(bx & (NREP - 1)) * 8192;
#pragma unroll
  for (int j = 0; j < 8; j++) {
    int base = ((rg * 8 + j) * 32 + d) * 4;
    atomicAdd(&grep[base + 0], acc[j][0]);
    atomicAdd(&grep[base + 1], acc[j][1]);
    atomicAdd(&grep[base + 2], acc[j][2]);
    atomicAdd(&grep[base + 3], acc[j][3]);
  }
}

__global__ __launch_bounds__(256) void ect_fin(
    const float* __restrict__ gacc, float* __restrict__ out) {
  __shared__ float red[4];
  int t = threadIdx.x;
  float s = 0.0f;
  for (int i = t; i < 2048; i += 256) {
    float a0 = 0.f, a1 = 0.f, a2 = 0.f, a3 = 0.f;
#pragma unroll
    for (int rep = 0; rep < NREP; rep++) {
      const float4 g = *(const float4*)(gacc + (size_t)rep * 8192 + i * 4);
      a0 += g.x; a1 += g.y; a2 += g.z; a3 += g.w;
    }
    s += a0 * a0 + a1 * a1 + (a0 + a1) * (a0 + a1)
       + a2 * a2 + a3 * a3 + (a2 + a3) * (a2 + a3);
  }
#pragma unroll
  for (int off = 32; off > 0; off >>= 1) s += __shfl_down(s, off, 64);
  if ((t & 63) == 0) red[t >> 6] = s;
  __syncthreads();
  if (t == 0) out[0] = (red[0] + red[1] + red[2] + red[3]) * (1.0f / 12288.0f);
}

extern "C" void kernel_launch(void* const* d_in, const int* in_sizes, int n_in,
                              void* d_out, int out_size, void* d_ws, size_t ws_size,
                              hipStream_t stream) {
  const float* pred = (const float*)d_in[0];
  const int* tgt = (const int*)d_in[1];
  float* ws = (float*)d_ws;
  float* out = (float*)d_out;

  const size_t part_floats = (size_t)GRID * 8192;       // 16 MB
  const size_t need = (part_floats + 8192 + 64) * sizeof(float);

  if (ws_size >= need) {
    float* part = ws;                                   // [512][8192], no init
    float* gacc2 = ws + part_floats;                    // 8192 + ticket
    hipMemsetAsync(gacc2, 0, (8192 + 64) * sizeof(float), stream);
    hipLaunchKernelGGL(ect_main_st, dim3(GRID), dim3(256), 0, stream,
                       pred, tgt, part);
    hipLaunchKernelGGL(ect_red, dim3(128), dim3(256), 0, stream,
                       part, gacc2, out);
  } else {
    // proven R0 fallback: replicated atomic accumulate + tiny fin
    float* gacc = ws;                                   // 4*8192 floats
    hipMemsetAsync(gacc, 0, (size_t)NREP * 8192 * sizeof(float), stream);
    hipLaunchKernelGGL(ect_main_at, dim3(GRID), dim3(256), 0, stream,
                       pred, tgt, gacc);
    hipLaunchKernelGGL(ect_fin, dim3(1), dim3(256), 0, stream, gacc, out);
  }
}

// Round 4
// 114.283 us; speedup vs baseline: 1.7783x; 1.0021x over previous
//
#include <hip/hip_runtime.h>
#include <cstdint>

// ECT loss, exact elementwise formulation (absmax 0.0 preserved).
// A[bc][r][d] = sum_p dw[b,p,c] * sigmoid(8*(lin_r - <x_p, v_d>)), c in {0,1};
// c2 = -(c0+c1); loss = mean over 12288.
//
// R4 (two levers on the proven R3 store-path structure):
//  * packed fp32: adjacent thresholds (r=2h,2h+1) paired into float2 so the
//    z-fma, s-mul and acc-fma all emit v_pk_fma_f32 / v_pk_mul_f32 (2x rate,
//    bit-identical per lane). ~52 -> ~36 VALU issues per voxel-thread.
//  * occupancy: 1024 blocks x 108 voxels (was 512 x 216) -> 4 blocks/CU
//    co-resident instead of 2; same total work, no cross-wave reduction.
// Fallback chain by ws_size: 1024-store -> 512-store -> atomic (R0 path).

typedef float f32x2 __attribute__((ext_vector_type(2)));

#define P_TOT 110592
#define NREP 4  // atomic fallback only

__device__ __forceinline__ uint32_t rotl32(uint32_t x, int d) {
  return (x << d) | (x >> (32 - d));
}

// threefry2x32, key = (0,17) — bit-exact vs jax (verified)
__device__ __forceinline__ void threefry_0_17(uint32_t x0, uint32_t x1,
                                              uint32_t& o0, uint32_t& o1) {
  const uint32_t ks0 = 0u, ks1 = 17u, ks2 = 0x1BD11BDAu ^ 0u ^ 17u;
  x0 += ks0; x1 += ks1;
#define R4(a,b,c,dd) \
  x0 += x1; x1 = rotl32(x1,(a)); x1 ^= x0; \
  x0 += x1; x1 = rotl32(x1,(b)); x1 ^= x0; \
  x0 += x1; x1 = rotl32(x1,(c)); x1 ^= x0; \
  x0 += x1; x1 = rotl32(x1,(dd)); x1 ^= x0;
  R4(13,15,26,6)   x0 += ks1; x1 += ks2 + 1u;
  R4(17,29,16,24)  x0 += ks2; x1 += ks0 + 2u;
  R4(13,15,26,6)   x0 += ks0; x1 += ks1 + 3u;
  R4(17,29,16,24)  x0 += ks1; x1 += ks2 + 4u;
  R4(13,15,26,6)   x0 += ks2; x1 += ks0 + 5u;
#undef R4
  o0 = x0; o1 = x1;
}

// XLA ErfInv32 — bit-exact vs jax (verified)
__device__ __forceinline__ float erfinv_f32(float x) {
  float w = -log1pf(-x * x);
  float p;
  if (w < 5.0f) {
    w = w - 2.5f;
    p = 2.81022636e-08f;
    p = fmaf(p, w, 3.43273939e-07f);
    p = fmaf(p, w, -3.5233877e-06f);
    p = fmaf(p, w, -4.39150654e-06f);
    p = fmaf(p, w, 0.00021858087f);
    p = fmaf(p, w, -0.00125372503f);
    p = fmaf(p, w, -0.00417768164f);
    p = fmaf(p, w, 0.246640727f);
    p = fmaf(p, w, 1.50140941f);
  } else {
    w = sqrtf(w) - 3.0f;
    p = -0.000200214257f;
    p = fmaf(p, w, 0.000100950558f);
    p = fmaf(p, w, 0.00134934322f);
    p = fmaf(p, w, 0.000337081863f);
    p = fmaf(p, w, 0.00573950773f);
    p = fmaf(p, w, -0.0076224613f);
    p = fmaf(p, w, 0.00943887047f);
    p = fmaf(p, w, 1.00167406f);
    p = fmaf(p, w, 2.83297682f);
  }
  return p * x;
}

// ---------- shared compute: accp[h][bc] = (acc[r=2h], acc[r=2h+1]) ----------
template <int VOXN>
__device__ __forceinline__ void ect_block_compute(
    const float* __restrict__ pred, const int* __restrict__ tgt,
    float* dirs, float4* voxdw, float4* voxc,
    int t, int bx, f32x2 accp[4][4]) {
  const int d = t & 31;
  const int rg = t >> 5;
  const int cbase = bx * VOXN;

  if (t < 96) {
    uint32_t o0, o1;
    threefry_0_17(0u, (uint32_t)t, o0, o1);
    uint32_t bits = o0 ^ o1;
    float u = __uint_as_float((bits >> 9) | 0x3F800000u) - 1.0f;
    const float lo = -0.99999994f;
    float v = fmaf(u, 2.0f, lo);
    v = fmaxf(v, lo);
    dirs[t] = 1.41421356237f * erfinv_f32(v);
  }
  __syncthreads();
  if (t < 32) {
    float a = dirs[t], b = dirs[32 + t], c = dirs[64 + t];
    float n = fmaxf(sqrtf(a * a + b * b + c * c), 1e-12f);
    dirs[t] = a / n; dirs[32 + t] = b / n; dirs[64 + t] = c / n;
  }
  if (t < VOXN) {
    int p = cbase + t;
    int ix = p / 2304; int rem = p - ix * 2304;
    int iy = rem / 48; int iz = rem - iy * 48;
    const float delta = 2.0f / 47.0f;
    voxc[t] = float4{(float)ix * delta - 1.0f, (float)iy * delta - 1.0f,
                     (float)iz * delta - 1.0f, 0.0f};
    float w[4];
#pragma unroll
    for (int b = 0; b < 2; b++) {
      const float* pb = pred + b * (3 * P_TOT) + p;
      float x0 = pb[0], x1 = pb[P_TOT], x2 = pb[2 * P_TOT];
      float m = fmaxf(x0, fmaxf(x1, x2));
      float e0 = __expf(x0 - m), e1 = __expf(x1 - m), e2 = __expf(x2 - m);
      float inv = 1.0f / (e0 + e1 + e2);
      int tg = tgt[b * P_TOT + p];
      w[b * 2 + 0] = e0 * inv - ((tg == 0) ? 1.0f : 0.0f);
      w[b * 2 + 1] = e1 * inv - ((tg == 1) ? 1.0f : 0.0f);
    }
    voxdw[t] = float4{w[0], w[1], w[2], w[3]};
  }
  __syncthreads();

  const float dir0 = dirs[d], dir1 = dirs[32 + d], dir2 = dirs[64 + d];
  const float radius = 1.1f * 1.7320508075688772f;
  const float step = (2.0f * radius) / 63.0f;
  f32x2 K2[4];
#pragma unroll
  for (int h = 0; h < 4; h++) {
    float l0 = fmaf((float)(rg * 8 + 2 * h), step, -radius);
    float l1 = fmaf((float)(rg * 8 + 2 * h + 1), step, -radius);
    K2[h] = f32x2{__expf(-8.0f * l0), __expf(-8.0f * l1)};
  }
  const f32x2 one2 = {1.0f, 1.0f};
#pragma unroll
  for (int h = 0; h < 4; h++)
#pragma unroll
    for (int bc = 0; bc < 4; bc++) accp[h][bc] = f32x2{0.0f, 0.0f};

#pragma unroll 4
  for (int v = 0; v < VOXN; v++) {
    float4 c = voxc[v];
    float4 w = voxdw[v];
    float nh = fmaf(c.z, dir2, fmaf(c.y, dir1, c.x * dir0));
    float E = __expf(8.0f * nh);              // <= e^13.9, no overflow
    f32x2 E2 = {E, E};
    f32x2 wx = {w.x, w.x}, wy = {w.y, w.y}, wz = {w.z, w.z}, ww = {w.w, w.w};
#pragma unroll
    for (int h = 0; h < 4; h++) {
      // z = 1 + E*K  (packed; 1..4.4e12)
      f32x2 z2 = __builtin_elementwise_fma(E2, K2[h], one2);
      // paired reciprocal: product <= 2e25, no overflow
      float pz = z2.x * z2.y;
      float rr = __builtin_amdgcn_rcpf(pz);
      f32x2 rr2 = {rr, rr};
      f32x2 s01 = z2.yx * rr2;   // (sig for r=2h, sig for r=2h+1)
      accp[h][0] = __builtin_elementwise_fma(wx, s01, accp[h][0]);
      accp[h][1] = __builtin_elementwise_fma(wy, s01, accp[h][1]);
      accp[h][2] = __builtin_elementwise_fma(wz, s01, accp[h][2]);
      accp[h][3] = __builtin_elementwise_fma(ww, s01, accp[h][3]);
    }
  }
}

// ---------- store path ----------
template <int VOXN>
__global__ __launch_bounds__(256, 2) void ect_main_st(
    const float* __restrict__ pred, const int* __restrict__ tgt,
    float* __restrict__ part) {
  __shared__ float dirs[96];
  __shared__ float4 voxdw[VOXN];
  __shared__ float4 voxc[VOXN];
  const int t = threadIdx.x;
  const int bx = blockIdx.x;
  const int d = t & 31;
  const int rg = t >> 5;
  f32x2 accp[4][4];
  ect_block_compute<VOXN>(pred, tgt, dirs, voxdw, voxc, t, bx, accp);

  float4* prt = (float4*)part + (size_t)bx * 2048;
#pragma unroll
  for (int h = 0; h < 4; h++) {
    prt[(rg * 8 + 2 * h) * 32 + d] =
        float4{accp[h][0].x, accp[h][1].x, accp[h][2].x, accp[h][3].x};
    prt[(rg * 8 + 2 * h + 1) * 32 + d] =
        float4{accp[h][0].y, accp[h][1].y, accp[h][2].y, accp[h][3].y};
  }
}

__global__ __launch_bounds__(256) void ect_red(
    const float* __restrict__ part, float* __restrict__ gacc2,
    float* __restrict__ out, int ngrid) {
  __shared__ float redf[4];
  __shared__ int islast;
  const int t = threadIdx.x;
  const int rc = blockIdx.x >> 3;       // slice chunk (32 slices each)
  const int cc = blockIdx.x & 7;        // column chunk (256 float4)
  const int c4 = cc * 256 + t;          // float4 column in [0, 2048)
  const float4* p4 = (const float4*)part;

  float a0 = 0.f, a1 = 0.f, a2 = 0.f, a3 = 0.f;
#pragma unroll 8
  for (int r = rc * 32; r < rc * 32 + 32; ++r) {
    float4 v = p4[(size_t)r * 2048 + c4];   // 1KB-coalesced per wave per r
    a0 += v.x; a1 += v.y; a2 += v.z; a3 += v.w;
  }
  atomicAdd(&gacc2[c4 * 4 + 0], a0);
  atomicAdd(&gacc2[c4 * 4 + 1], a1);
  atomicAdd(&gacc2[c4 * 4 + 2], a2);
  atomicAdd(&gacc2[c4 * 4 + 3], a3);

  __syncthreads();                       // drains vmcnt(0) per wave
  unsigned int* cnt = (unsigned int*)(gacc2 + 8192);
  if (t == 0) {
    unsigned int old = __hip_atomic_fetch_add(cnt, 1u, __ATOMIC_RELAXED,
                                              __HIP_MEMORY_SCOPE_AGENT);
    islast = (old == (unsigned int)(ngrid - 1)) ? 1 : 0;
  }
  __syncthreads();
  if (islast) {
    float s = 0.0f;
    for (int i = t; i < 2048; i += 256) {  // i = r*32 + d
      const unsigned long long* p64 =
          (const unsigned long long*)(gacc2 + i * 4);
      unsigned long long q0 = __hip_atomic_load(p64, __ATOMIC_RELAXED,
                                                __HIP_MEMORY_SCOPE_AGENT);
      unsigned long long q1 = __hip_atomic_load(p64 + 1, __ATOMIC_RELAXED,
                                                __HIP_MEMORY_SCOPE_AGENT);
      float b0 = __uint_as_float((unsigned int)q0);
      float b1 = __uint_as_float((unsigned int)(q0 >> 32));
      float b2 = __uint_as_float((unsigned int)q1);
      float b3 = __uint_as_float((unsigned int)(q1 >> 32));
      s += b0 * b0 + b1 * b1 + (b0 + b1) * (b0 + b1)
         + b2 * b2 + b3 * b3 + (b2 + b3) * (b2 + b3);
    }
#pragma unroll
    for (int off = 32; off > 0; off >>= 1) s += __shfl_down(s, off, 64);
    if ((t & 63) == 0) redf[t >> 6] = s;
    __syncthreads();
    if (t == 0)
      out[0] = (redf[0] + redf[1] + redf[2] + redf[3]) * (1.0f / 12288.0f);
  }
}

// ---------- atomic fallback (proven R0 structure) ----------
__global__ __launch_bounds__(256, 2) void ect_main_at(
    const float* __restrict__ pred, const int* __restrict__ tgt,
    float* __restrict__ gacc) {
  __shared__ float dirs[96];
  __shared__ float4 voxdw[216];
  __shared__ float4 voxc[216];
  const int t = threadIdx.x;
  const int bx = blockIdx.x;
  const int d = t & 31;
  const int rg = t >> 5;
  f32x2 accp[4][4];
  ect_block_compute<216>(pred, tgt, dirs, voxdw, voxc, t, bx, accp);

  float* grep = gacc + (size_t)(bx & (NREP - 1)) * 8192;
#pragma unroll
  for (int h = 0; h < 4; h++) {
    int b0 = ((rg * 8 + 2 * h) * 32 + d) * 4;
    int b1 = ((rg * 8 + 2 * h + 1) * 32 + d) * 4;
    atomicAdd(&grep[b0 + 0], accp[h][0].x);
    atomicAdd(&grep[b0 + 1], accp[h][1].x);
    atomicAdd(&grep[b0 + 2], accp[h][2].x);
    atomicAdd(&grep[b0 + 3], accp[h][3].x);
    atomicAdd(&grep[b1 + 0], accp[h][0].y);
    atomicAdd(&grep[b1 + 1], accp[h][1].y);
    atomicAdd(&grep[b1 + 2], accp[h][2].y);
    atomicAdd(&grep[b1 + 3], accp[h][3].y);
  }
}

__global__ __launch_bounds__(256) void ect_fin(
    const float* __restrict__ gacc, float* __restrict__ out) {
  __shared__ float red[4];
  int t = threadIdx.x;
  float s = 0.0f;
  for (int i = t; i < 2048; i += 256) {
    float a0 = 0.f, a1 = 0.f, a2 = 0.f, a3 = 0.f;
#pragma unroll
    for (int rep = 0; rep < NREP; rep++) {
      const float4 g = *(const float4*)(gacc + (size_t)rep * 8192 + i * 4);
      a0 += g.x; a1 += g.y; a2 += g.z; a3 += g.w;
    }
    s += a0 * a0 + a1 * a1 + (a0 + a1) * (a0 + a1)
       + a2 * a2 + a3 * a3 + (a2 + a3) * (a2 + a3);
  }
#pragma unroll
  for (int off = 32; off > 0; off >>= 1) s += __shfl_down(s, off, 64);
  if ((t & 63) == 0) red[t >> 6] = s;
  __syncthreads();
  if (t == 0) out[0] = (red[0] + red[1] + red[2] + red[3]) * (1.0f / 12288.0f);
}

extern "C" void kernel_launch(void* const* d_in, const int* in_sizes, int n_in,
                              void* d_out, int out_size, void* d_ws, size_t ws_size,
                              hipStream_t stream) {
  const float* pred = (const float*)d_in[0];
  const int* tgt = (const int*)d_in[1];
  float* ws = (float*)d_ws;
  float* out = (float*)d_out;

  const size_t need1024 = ((size_t)1024 * 8192 + 8192 + 64) * sizeof(float);
  const size_t need512 = ((size_t)512 * 8192 + 8192 + 64) * sizeof(float);

  if (ws_size >= need1024) {
    // 1024 blocks x 108 voxels: 4 blocks/CU co-resident
    float* part = ws;                                   // [1024][8192]
    float* gacc2 = ws + (size_t)1024 * 8192;
    hipMemsetAsync(gacc2, 0, (8192 + 64) * sizeof(float), stream);
    hipLaunchKernelGGL(ect_main_st<108>, dim3(1024), dim3(256), 0, stream,
                       pred, tgt, part);
    hipLaunchKernelGGL(ect_red, dim3(256), dim3(256), 0, stream,
                       part, gacc2, out, 256);
  } else if (ws_size >= need512) {
    float* part = ws;                                   // [512][8192]
    float* gacc2 = ws + (size_t)512 * 8192;
    hipMemsetAsync(gacc2, 0, (8192 + 64) * sizeof(float), stream);
    hipLaunchKernelGGL(ect_main_st<216>, dim3(512), dim3(256), 0, stream,
                       pred, tgt, part);
    hipLaunchKernelGGL(ect_red, dim3(128), dim3(256), 0, stream,
                       part, gacc2, out, 128);
  } else {
    float* gacc = ws;                                   // 4*8192 floats
    hipMemsetAsync(gacc, 0, (size_t)NREP * 8192 * sizeof(float), stream);
    hipLaunchKernelGGL(ect_main_at, dim3(512), dim3(256), 0, stream,
                       pred, tgt, gacc);
    hipLaunchKernelGGL(ect_fin, dim3(1), dim3(256), 0, stream, gacc, out);
  }
}